// Round 6
// baseline (278.450 us; speedup 1.0000x reference)
//
#include <hip/hip_runtime.h>
#include <hip/hip_bf16.h>
#include <cstdint>
#include <cstddef>

#define L_SEQ 4096
#define BATCH_N 4
#define HID 1024
#define DH 256
// log2(0.96875)
#define LOG2_GAMMA (-0.045803689613124953f)

typedef __attribute__((ext_vector_type(8))) short short8;
typedef __attribute__((ext_vector_type(4))) float floatx4;

__device__ __forceinline__ unsigned short f2bf(float f) {
    union { float f; unsigned int u; } v; v.f = f;
    unsigned int r = (v.u + 0x7FFFu + ((v.u >> 16) & 1u)) >> 16;  // RNE
    return (unsigned short)r;
}

__device__ __forceinline__ void async_copy16(const unsigned short* gsrc,
                                             unsigned short* lds) {
    __builtin_amdgcn_global_load_lds(
        (const __attribute__((address_space(1))) unsigned int*)gsrc,
        (__attribute__((address_space(3))) unsigned int*)lds, 16, 0, 0);
}

// NOTE (rounds 4/5 failures): gfx950 v_sin_f32/v_cos_f32 are only ~11-bit
// absolute accurate (~5e-4): raw __sinf failed at 5.0e-4 and a near-exact
// Cody-Waite reduction feeding v_sin still failed at 5.8e-4. libm sincosf
// (round 3) passes at 6.1e-5. Keep libm here — tolerance is 2.5e-4.

// ---------------------------------------------------------------------------
// Kernel B: W_{Q,K,V} (1024x256 fp32 each) -> Wt bf16 [768][1024] (transposed,
// concatenated: rows 0..255 = Q feats, 256..511 = K, 512..767 = V)
// ---------------------------------------------------------------------------
__global__ __launch_bounds__(256) void transpose_w_kernel(
    const float* __restrict__ WQ, const float* __restrict__ WK,
    const float* __restrict__ WV, unsigned short* __restrict__ Wt)
{
    __shared__ float Ts[64][68];   // [n_local][k_local]
    const int n0 = blockIdx.x * 64;     // 0..704
    const int k0 = blockIdx.y * 64;     // 0..960
    const int seg = n0 >> 8;
    const float* __restrict__ W = (seg == 0) ? WQ : (seg == 1) ? WK : WV;
    const int nl0 = n0 & 255;

    const int t  = threadIdx.x;
    const int r  = t >> 4;          // 0..15
    const int c4 = (t & 15) * 4;
    #pragma unroll
    for (int i = 0; i < 4; ++i) {
        const int kk = r + i * 16;
        const float4 v = *(const float4*)&W[(size_t)(k0 + kk) * DH + nl0 + c4];
        Ts[c4 + 0][kk] = v.x;
        Ts[c4 + 1][kk] = v.y;
        Ts[c4 + 2][kk] = v.z;
        Ts[c4 + 3][kk] = v.w;
    }
    __syncthreads();
    const int rn = t >> 3;          // 0..31
    const int c8 = (t & 7) * 8;
    #pragma unroll
    for (int i = 0; i < 2; ++i) {
        const int rr = rn + i * 32;
        ushort4 p0, p1;
        p0.x = f2bf(Ts[rr][c8 + 0]); p0.y = f2bf(Ts[rr][c8 + 1]);
        p0.z = f2bf(Ts[rr][c8 + 2]); p0.w = f2bf(Ts[rr][c8 + 3]);
        p1.x = f2bf(Ts[rr][c8 + 4]); p1.y = f2bf(Ts[rr][c8 + 5]);
        p1.z = f2bf(Ts[rr][c8 + 6]); p1.w = f2bf(Ts[rr][c8 + 7]);
        unsigned short* dst = &Wt[(size_t)(n0 + rr) * HID + k0 + c8];
        *(ushort4*)dst       = p0;
        *(ushort4*)(dst + 4) = p1;
    }
}

// ---------------------------------------------------------------------------
// Kernel C: QKV projection via bf16 MFMA, BK=64 two-panel LDS, X read as fp32
// with in-register bf16 convert. Output-transposed C: row=feature, col=pos.
// 1-D grid 768, XCD-swizzled: xcd = idx&7 owns p-tiles xcd*16..xcd*16+15.
// ---------------------------------------------------------------------------
__global__ __launch_bounds__(256, 3) void gemm_qkv_kernel(
    const unsigned short* __restrict__ Wt,   // [768][1024] bf16
    const float* __restrict__ X,             // [16384][1024] fp32
    unsigned short* __restrict__ Qo,
    unsigned short* __restrict__ Ko,
    unsigned short* __restrict__ VtG)
{
    __shared__ unsigned short Wa[2][128][32];   // 16 KB: panel h = k-half
    __shared__ unsigned short Xs[2][128][32];   // 16 KB

    const int idx = blockIdx.x;
    const int xcd = idx & 7;
    const int j   = idx >> 3;              // 0..95
    const int n0  = (j % 6) * 128;         // feature tile
    const int p0  = (xcd * 16 + (j / 6)) * 128;  // pos tile (XCD-local range)

    const int t    = threadIdx.x;
    const int w    = t >> 6;
    const int lane = t & 63;
    const int quad = lane >> 4;
    const int l16  = lane & 15;
    const int wn   = (w & 1) * 64;
    const int wp   = (w >> 1) * 64;

    const int arow = lane >> 2;        // 0..15 within 16-row chunk
    const int acol = (lane & 3) * 8;   // shorts

    const int rb = t >> 1;             // B-staging row 0..127
    const int hb = t & 1;              // B-staging k-half

    floatx4 acc[4][4];
    #pragma unroll
    for (int i = 0; i < 4; ++i)
        #pragma unroll
        for (int jj = 0; jj < 4; ++jj) acc[i][jj] = (floatx4){0.f, 0.f, 0.f, 0.f};

    const float* xsrc0 = &X[(size_t)(p0 + rb) * HID + hb * 32];

    for (int k0 = 0; k0 < HID; k0 += 64) {
        // issue B global loads early (before barrier)
        float4 xv[8];
        #pragma unroll
        for (int i = 0; i < 8; ++i)
            xv[i] = ((const float4*)(xsrc0 + k0))[i];

        __syncthreads();   // previous tile's frag reads complete

        // A: async global->LDS (two 32-k panels, 16-row chunks)
        #pragma unroll
        for (int s = 0; s < 4; ++s) {
            const int panel = s & 1;
            const int rch   = w * 32 + (s >> 1) * 16;
            const unsigned short* ga =
                &Wt[(size_t)(n0 + rch + arow) * HID + k0 + panel * 32 + acol];
            async_copy16(ga, &Wa[panel][rch][0]);
        }
        // B: cvt fp32 -> bf16, write LDS
        {
            unsigned short* bd = &Xs[hb][rb][0];
            #pragma unroll
            for (int c = 0; c < 4; ++c) {
                const float4 v0 = xv[c * 2], v1 = xv[c * 2 + 1];
                union { unsigned short s[8]; uint4 u; } pk;
                pk.s[0] = f2bf(v0.x); pk.s[1] = f2bf(v0.y);
                pk.s[2] = f2bf(v0.z); pk.s[3] = f2bf(v0.w);
                pk.s[4] = f2bf(v1.x); pk.s[5] = f2bf(v1.y);
                pk.s[6] = f2bf(v1.z); pk.s[7] = f2bf(v1.w);
                *(uint4*)&bd[c * 8] = pk.u;
            }
        }
        __syncthreads();   // staging visible (compiler drains vmcnt here)

        #pragma unroll
        for (int h = 0; h < 2; ++h) {
            short8 af[4], bfv[4];
            #pragma unroll
            for (int nt = 0; nt < 4; ++nt)
                af[nt] = *(const short8*)&Wa[h][wn + nt * 16 + l16][quad * 8];
            #pragma unroll
            for (int pt = 0; pt < 4; ++pt)
                bfv[pt] = *(const short8*)&Xs[h][wp + pt * 16 + l16][quad * 8];
            #pragma unroll
            for (int nt = 0; nt < 4; ++nt)
                #pragma unroll
                for (int pt = 0; pt < 4; ++pt)
                    acc[nt][pt] = __builtin_amdgcn_mfma_f32_16x16x32_bf16(
                        af[nt], bfv[pt], acc[nt][pt], 0, 0, 0);
        }
    }

    // ---- epilogue: xpos on Q/K, direct transposed store for V ----
    const int seg = n0 >> 8;     // 0=Q 1=K 2=V
    #pragma unroll
    for (int nt = 0; nt < 4; ++nt) {
        const int nfeat = n0 + wn + nt * 16 + quad * 4;
        const int d0 = nfeat & 255;
        #pragma unroll
        for (int pt = 0; pt < 4; ++pt) {
            const int pg  = p0 + wp + pt * 16 + l16;
            const int b   = pg >> 12;
            const int pos = pg & (L_SEQ - 1);
            if (seg == 2) {
                #pragma unroll
                for (int g = 0; g < 4; ++g)
                    VtG[(((size_t)(b * 256 + d0 + g)) << 12) + pos] =
                        f2bf(acc[nt][pt][g]);
            } else {
                const float e = (float)pos * (1.0f / 512.0f);
                float res[4];
                #pragma unroll
                for (int h = 0; h < 4; h += 2) {
                    const int d  = d0 + h;
                    const int i2 = d >> 1;
                    const float sb = ((float)d + 102.4f) * (1.0f / 358.4f);
                    float sc = exp2f(log2f(sb) * e);
                    if (seg == 1) sc = 1.0f / sc;
                    const float invf = exp2f(-13.287712379549449f *
                                             ((float)i2 * (1.0f / 128.0f)));
                    const float th = (float)pos * invf;  // fp32, matches ref
                    float s, c;
                    sincosf(th, &s, &c);   // libm: accurate (HW v_sin is ~11-bit)
                    const float cs = c * sc, ss = s * sc;
                    const float xe = acc[nt][pt][h], xo = acc[nt][pt][h + 1];
                    res[h]     = xe * cs - xo * ss;
                    res[h + 1] = xo * cs + xe * ss;
                }
                ushort4 pk;
                pk.x = f2bf(res[0]); pk.y = f2bf(res[1]);
                pk.z = f2bf(res[2]); pk.w = f2bf(res[3]);
                unsigned short* orow =
                    ((seg == 0) ? Qo : Ko) + (size_t)pg * DH + d0;
                *(ushort4*)orow = pk;
            }
        }
    }
}

// ---------------------------------------------------------------------------
// Kernel D: windowed retention, 32-row q-tiles, Q frags in registers.
//   4 waves: rw=(w>>1)*16 row-half; ws=w&1 splits keys (S) / cols (PV).
//   grid (128,4) -> 2 blocks/CU, 8 waves/CU. LDS ~40 KB.
// ---------------------------------------------------------------------------
__global__ __launch_bounds__(256, 2) void retention_kernel(
    const unsigned short* __restrict__ Q,
    const unsigned short* __restrict__ K,
    const unsigned short* __restrict__ VtG,
    float* __restrict__ O)
{
    __shared__ short Ks[32][264];   // 16.9 KB
    __shared__ short Vt[256][40];   // 20.5 KB  [col][key]
    __shared__ short Ss[32][40];    //  2.6 KB  [q][key]

    const int qt = blockIdx.x;          // 0..127
    const int b  = blockIdx.y;
    const int t  = threadIdx.x;
    const int q0 = qt * 32;

    const int w    = t >> 6;
    const int lane = t & 63;
    const int quad = lane >> 4;
    const int l16  = lane & 15;
    const int rw   = (w >> 1) * 16;     // 0 or 16
    const int ws   = w & 1;             // key-half (S) / col-half (PV)

    const size_t rbase = (size_t)b * L_SEQ * DH;
    const size_t vbase = ((size_t)b * DH) << 12;

    // Q fragments straight from global into registers (k-loop invariant)
    short8 qf[8];
    {
        const unsigned short* qrow =
            Q + rbase + (size_t)(q0 + rw + l16) * DH + quad * 8;
        #pragma unroll
        for (int d8 = 0; d8 < 8; ++d8)
            qf[d8] = *(const short8*)(qrow + d8 * 32);
    }

    floatx4 o[8];
    #pragma unroll
    for (int f = 0; f < 8; ++f) o[f] = (floatx4){0.f, 0.f, 0.f, 0.f};

    int kstart = q0 - 512;
    if (kstart < 0) kstart = 0;

    for (int k0 = kstart; k0 <= q0; k0 += 32) {
        __syncthreads();   // previous iteration's LDS reads complete
        // stage K tile 32 x 256
        {
            const unsigned short* src = K + rbase + (size_t)k0 * DH;
            #pragma unroll
            for (int i = 0; i < 4; ++i) {
                const int row = i * 8 + (t >> 5);
                const int col = (t & 31) * 8;
                *(uint4*)&Ks[row][col] = *(const uint4*)&src[row * DH + col];
            }
        }
        // stage V^T tile: Vt[c][0..31]
        {
            const int koff = (t & 7) * 4;
            #pragma unroll
            for (int i = 0; i < 8; ++i) {
                const int c = (t >> 3) + 32 * i;
                *(uint2*)&Vt[c][koff] =
                    *(const uint2*)&VtG[vbase + ((size_t)c << 12) + k0 + koff];
            }
        }
        __syncthreads();

        // S = Q.K^T : this wave's 16 q-rows x its 16-key half
        {
            floatx4 s = (floatx4){0.f, 0.f, 0.f, 0.f};
            #pragma unroll
            for (int d8 = 0; d8 < 8; ++d8) {
                const short8 bfr =
                    *(const short8*)&Ks[ws * 16 + l16][d8 * 32 + quad * 8];
                s = __builtin_amdgcn_mfma_f32_16x16x32_bf16(qf[d8], bfr, s, 0, 0, 0);
            }
            const int kpos = k0 + ws * 16 + l16;
            #pragma unroll
            for (int g = 0; g < 4; ++g) {
                const int qpos = q0 + rw + quad * 4 + g;
                const int d = qpos - kpos;
                const float p = (d >= 0) ? s[g] * exp2f((float)d * LOG2_GAMMA) : 0.0f;
                Ss[rw + quad * 4 + g][ws * 16 + l16] = (short)f2bf(p);
            }
        }
        __syncthreads();

        // O += P.V : this wave's 16 q-rows x its 128-col half (full 32 keys)
        {
            const short8 a = *(const short8*)&Ss[rw + l16][quad * 8];
            #pragma unroll
            for (int f = 0; f < 8; ++f) {
                const short8 bfr =
                    *(const short8*)&Vt[ws * 128 + f * 16 + l16][quad * 8];
                o[f] = __builtin_amdgcn_mfma_f32_16x16x32_bf16(a, bfr, o[f], 0, 0, 0);
            }
        }
    }

    #pragma unroll
    for (int f = 0; f < 8; ++f) {
        #pragma unroll
        for (int g = 0; g < 4; ++g) {
            const int qpos = q0 + rw + quad * 4 + g;
            O[rbase + (size_t)qpos * DH + ws * 128 + f * 16 + l16] = o[f][g];
        }
    }
}

// ---------------------------------------------------------------------------
extern "C" void kernel_launch(void* const* d_in, const int* in_sizes, int n_in,
                              void* d_out, int out_size, void* d_ws, size_t ws_size,
                              hipStream_t stream)
{
    const float* X  = (const float*)d_in[0];
    const float* WQ = (const float*)d_in[1];
    const float* WK = (const float*)d_in[2];
    const float* WV = (const float*)d_in[3];
    float* out = (float*)d_out;

    const size_t per = (size_t)BATCH_N * L_SEQ * DH;   // 4,194,304
    unsigned short* Qw  = (unsigned short*)d_ws;
    unsigned short* Kw  = Qw + per;
    unsigned short* Vtw = Kw + per;
    unsigned short* Wtw = Vtw + per;   // 786,432 elems; total ~25.7 MB

    transpose_w_kernel<<<dim3(12, 16), 256, 0, stream>>>(WQ, WK, WV, Wtw);

    gemm_qkv_kernel<<<768, 256, 0, stream>>>(Wtw, X, Qw, Kw, Vtw);

    retention_kernel<<<dim3(L_SEQ / 32, BATCH_N), 256, 0, stream>>>(Qw, Kw, Vtw, out);
}

// Round 7
// 260.119 us; speedup vs baseline: 1.0705x; 1.0705x over previous
//
#include <hip/hip_runtime.h>
#include <hip/hip_bf16.h>
#include <cstdint>
#include <cstddef>

#define L_SEQ 4096
#define BATCH_N 4
#define HID 1024
#define DH 256
// log2(0.96875)
#define LOG2_GAMMA (-0.045803689613124953f)

typedef __attribute__((ext_vector_type(8))) short short8;
typedef __attribute__((ext_vector_type(4))) float floatx4;

__device__ __forceinline__ unsigned short f2bf(float f) {
    union { float f; unsigned int u; } v; v.f = f;
    unsigned int r = (v.u + 0x7FFFu + ((v.u >> 16) & 1u)) >> 16;  // RNE
    return (unsigned short)r;
}

__device__ __forceinline__ void async_copy16(const unsigned short* gsrc,
                                             unsigned short* lds) {
    __builtin_amdgcn_global_load_lds(
        (const __attribute__((address_space(1))) unsigned int*)gsrc,
        (__attribute__((address_space(3))) unsigned int*)lds, 16, 0, 0);
}

// NOTE (rounds 4/5): gfx950 v_sin/v_cos are only ~11-bit absolute (~5e-4
// fails the 2.5e-4 tolerance even with exact Cody-Waite reduction). libm
// sincosf passes at 6.1e-5. Keep libm.
// NOTE (round 6): fusing fp32->bf16 X-convert into the GEMM (register
// round-trip) + launch_bounds(256,3) regressed 54->145 us (VGPR 60,
// serialized loads). Keep the separate convert pass + async staging.

// ---------------------------------------------------------------------------
// Kernel A: X fp32 -> bf16
// ---------------------------------------------------------------------------
__global__ __launch_bounds__(256) void convert_x_kernel(
    const float* __restrict__ X, unsigned short* __restrict__ Xb)
{
    const int i = (blockIdx.x * 256 + threadIdx.x) * 4;
    const float4 v = *(const float4*)&X[i];
    ushort4 p;
    p.x = f2bf(v.x); p.y = f2bf(v.y); p.z = f2bf(v.z); p.w = f2bf(v.w);
    *(ushort4*)&Xb[i] = p;
}

// ---------------------------------------------------------------------------
// Kernel B: W_{Q,K,V} (1024x256 fp32 each) -> Wt bf16 [768][1024] transposed.
// ---------------------------------------------------------------------------
__global__ __launch_bounds__(256) void transpose_w_kernel(
    const float* __restrict__ WQ, const float* __restrict__ WK,
    const float* __restrict__ WV, unsigned short* __restrict__ Wt)
{
    __shared__ float Ts[64][68];
    const int n0 = blockIdx.x * 64;
    const int k0 = blockIdx.y * 64;
    const int seg = n0 >> 8;
    const float* __restrict__ W = (seg == 0) ? WQ : (seg == 1) ? WK : WV;
    const int nl0 = n0 & 255;

    const int t  = threadIdx.x;
    const int r  = t >> 4;
    const int c4 = (t & 15) * 4;
    #pragma unroll
    for (int i = 0; i < 4; ++i) {
        const int kk = r + i * 16;
        const float4 v = *(const float4*)&W[(size_t)(k0 + kk) * DH + nl0 + c4];
        Ts[c4 + 0][kk] = v.x;
        Ts[c4 + 1][kk] = v.y;
        Ts[c4 + 2][kk] = v.z;
        Ts[c4 + 3][kk] = v.w;
    }
    __syncthreads();
    const int rn = t >> 3;
    const int c8 = (t & 7) * 8;
    #pragma unroll
    for (int i = 0; i < 2; ++i) {
        const int rr = rn + i * 32;
        ushort4 p0, p1;
        p0.x = f2bf(Ts[rr][c8 + 0]); p0.y = f2bf(Ts[rr][c8 + 1]);
        p0.z = f2bf(Ts[rr][c8 + 2]); p0.w = f2bf(Ts[rr][c8 + 3]);
        p1.x = f2bf(Ts[rr][c8 + 4]); p1.y = f2bf(Ts[rr][c8 + 5]);
        p1.z = f2bf(Ts[rr][c8 + 6]); p1.w = f2bf(Ts[rr][c8 + 7]);
        unsigned short* dst = &Wt[(size_t)(n0 + rr) * HID + k0 + c8];
        *(ushort4*)dst       = p0;
        *(ushort4*)(dst + 4) = p1;
    }
}

// ---------------------------------------------------------------------------
// Kernel C: QKV projection (r3 structure: BK=32, async_copy16 both operands,
// bf16 X) + XCD swizzle (r6: FETCH 101->39 MB). Output-transposed C.
// ---------------------------------------------------------------------------
__global__ __launch_bounds__(256) void gemm_qkv_kernel(
    const unsigned short* __restrict__ Wt,   // [768][1024] bf16
    const unsigned short* __restrict__ Xb,   // [16384][1024] bf16
    unsigned short* __restrict__ Qo,
    unsigned short* __restrict__ Ko,
    unsigned short* __restrict__ VtG)
{
    __shared__ unsigned short Wa[128][32];   // 8 KB
    __shared__ unsigned short Xs[128][32];   // 8 KB

    const int idx = blockIdx.x;
    const int xcd = idx & 7;
    const int j   = idx >> 3;                    // 0..95
    const int n0  = (j % 6) * 128;               // feature tile
    const int p0  = (xcd * 16 + (j / 6)) * 128;  // pos tile (XCD-local)

    const int t    = threadIdx.x;
    const int w    = t >> 6;
    const int lane = t & 63;
    const int quad = lane >> 4;
    const int l16  = lane & 15;
    const int wn   = (w & 1) * 64;
    const int wp   = (w >> 1) * 64;

    const int srow = w * 32 + (lane >> 2);   // staging row (+is*16)
    const int scol = (lane & 3) * 8;         // staging col (shorts)

    floatx4 acc[4][4];
    #pragma unroll
    for (int i = 0; i < 4; ++i)
        #pragma unroll
        for (int jj = 0; jj < 4; ++jj) acc[i][jj] = (floatx4){0.f, 0.f, 0.f, 0.f};

    for (int k0 = 0; k0 < HID; k0 += 32) {
        __syncthreads();   // previous tile's frag reads complete
        #pragma unroll
        for (int is = 0; is < 2; ++is) {
            const unsigned short* ga =
                &Wt[(size_t)(n0 + srow + is * 16) * HID + k0 + scol];
            const unsigned short* gb =
                &Xb[(size_t)(p0 + srow + is * 16) * HID + k0 + scol];
            async_copy16(ga, &Wa[w * 32 + is * 16][0]);
            async_copy16(gb, &Xs[w * 32 + is * 16][0]);
        }
        __syncthreads();   // staging visible

        short8 af[4], bfv[4];
        #pragma unroll
        for (int nt = 0; nt < 4; ++nt)
            af[nt] = *(const short8*)&Wa[wn + nt * 16 + l16][quad * 8];
        #pragma unroll
        for (int pt = 0; pt < 4; ++pt)
            bfv[pt] = *(const short8*)&Xs[wp + pt * 16 + l16][quad * 8];
        #pragma unroll
        for (int nt = 0; nt < 4; ++nt)
            #pragma unroll
            for (int pt = 0; pt < 4; ++pt)
                acc[nt][pt] = __builtin_amdgcn_mfma_f32_16x16x32_bf16(
                    af[nt], bfv[pt], acc[nt][pt], 0, 0, 0);
    }

    // ---- epilogue: xpos on Q/K, direct transposed store for V ----
    const int seg = n0 >> 8;     // 0=Q 1=K 2=V
    #pragma unroll
    for (int nt = 0; nt < 4; ++nt) {
        const int nfeat = n0 + wn + nt * 16 + quad * 4;
        const int d0 = nfeat & 255;
        #pragma unroll
        for (int pt = 0; pt < 4; ++pt) {
            const int pg  = p0 + wp + pt * 16 + l16;
            const int b   = pg >> 12;
            const int pos = pg & (L_SEQ - 1);
            if (seg == 2) {
                #pragma unroll
                for (int g = 0; g < 4; ++g)
                    VtG[(((size_t)(b * 256 + d0 + g)) << 12) + pos] =
                        f2bf(acc[nt][pt][g]);
            } else {
                const float e = (float)pos * (1.0f / 512.0f);
                float res[4];
                #pragma unroll
                for (int h = 0; h < 4; h += 2) {
                    const int d  = d0 + h;
                    const int i2 = d >> 1;
                    const float sb = ((float)d + 102.4f) * (1.0f / 358.4f);
                    float sc = exp2f(log2f(sb) * e);
                    if (seg == 1) sc = 1.0f / sc;
                    const float invf = exp2f(-13.287712379549449f *
                                             ((float)i2 * (1.0f / 128.0f)));
                    const float th = (float)pos * invf;
                    float s, c;
                    sincosf(th, &s, &c);   // libm (HW v_sin is ~11-bit: fails)
                    const float cs = c * sc, ss = s * sc;
                    const float xe = acc[nt][pt][h], xo = acc[nt][pt][h + 1];
                    res[h]     = xe * cs - xo * ss;
                    res[h + 1] = xo * cs + xe * ss;
                }
                ushort4 pk;
                pk.x = f2bf(res[0]); pk.y = f2bf(res[1]);
                pk.z = f2bf(res[2]); pk.w = f2bf(res[3]);
                unsigned short* orow =
                    ((seg == 0) ? Qo : Ko) + (size_t)pg * DH + d0;
                *(ushort4*)orow = pk;
            }
        }
    }
}

// ---------------------------------------------------------------------------
// Kernel D: windowed retention. 64-row q-tiles, K-tile 64 (<=9 iters).
// Wave w fully owns q-rows w*16..w*16+15: S (4x8 MFMA) -> decay -> Ss
// (wave-private, NO barrier) -> PV (2x16 MFMA, 256 cols). K/V tiles staged
// via register prefetch issued one full iteration ahead; 2 barriers/iter.
// LDS ~80 KB -> 1 block/CU, grid (64,4) = 256 blocks.
// ---------------------------------------------------------------------------
__global__ __launch_bounds__(256) void retention_kernel(
    const unsigned short* __restrict__ Q,
    const unsigned short* __restrict__ K,
    const unsigned short* __restrict__ VtG,
    float* __restrict__ O)
{
    __shared__ short Ks[64][264];      // 33.8 KB
    __shared__ short Vt[256][72];      // 36.9 KB  [col][key0..63 +pad]
    __shared__ short Ss[4][16][72];    //  9.2 KB  wave-private [row][key]

    const int qt = blockIdx.x;          // 0..63
    const int b  = blockIdx.y;
    const int t  = threadIdx.x;
    const int q0 = qt * 64;

    const int w    = t >> 6;
    const int lane = t & 63;
    const int quad = lane >> 4;
    const int l16  = lane & 15;
    const int w16  = w * 16;

    const size_t rbase = (size_t)b * L_SEQ * DH;
    const size_t vbase = ((size_t)b * DH) << 12;

    // staging index maps (per thread)
    const int krow = t >> 5;            // + i*8 : K row
    const int kcol = (t & 31) * 8;      // shorts
    const int vc   = t >> 3;            // + i*32 : Vt col
    const int vk   = (t & 7) * 8;       // shorts within 64-key tile

    // Q fragments: k-loop invariant, registers
    short8 qf[8];
    {
        const unsigned short* qrow =
            Q + rbase + (size_t)(q0 + w16 + l16) * DH + quad * 8;
        #pragma unroll
        for (int d8 = 0; d8 < 8; ++d8)
            qf[d8] = *(const short8*)(qrow + d8 * 32);
    }

    floatx4 o[16];
    #pragma unroll
    for (int f = 0; f < 16; ++f) o[f] = (floatx4){0.f, 0.f, 0.f, 0.f};

    int kstart = q0 - 512;
    if (kstart < 0) kstart = 0;

    // prefetch first tile into registers
    uint4 kreg[8], vreg[8];
    #pragma unroll
    for (int i = 0; i < 8; ++i) {
        kreg[i] = *(const uint4*)&K[rbase + (size_t)(kstart + i * 8 + krow) * DH + kcol];
        vreg[i] = *(const uint4*)&VtG[vbase + ((size_t)(vc + i * 32) << 12) + kstart + vk];
    }

    for (int k0 = kstart; k0 < q0 + 64; k0 += 64) {
        __syncthreads();   // all waves done reading previous tile
        // registers -> LDS
        #pragma unroll
        for (int i = 0; i < 8; ++i) {
            *(uint4*)&Ks[i * 8 + krow][kcol] = kreg[i];
            *(uint4*)&Vt[vc + i * 32][vk]    = vreg[i];
        }
        // issue NEXT tile's global loads (hidden under this tile's compute)
        {
            const int kn = (k0 + 64 < q0 + 64) ? (k0 + 64) : kstart;
            #pragma unroll
            for (int i = 0; i < 8; ++i) {
                kreg[i] = *(const uint4*)&K[rbase + (size_t)(kn + i * 8 + krow) * DH + kcol];
                vreg[i] = *(const uint4*)&VtG[vbase + ((size_t)(vc + i * 32) << 12) + kn + vk];
            }
        }
        __syncthreads();   // staged tile visible

        // S = Q.K^T : 16 q-rows x 64 keys; decay; P -> wave-private Ss
        #pragma unroll
        for (int nt = 0; nt < 4; ++nt) {
            floatx4 s = (floatx4){0.f, 0.f, 0.f, 0.f};
            #pragma unroll
            for (int d8 = 0; d8 < 8; ++d8) {
                const short8 bfr =
                    *(const short8*)&Ks[nt * 16 + l16][d8 * 32 + quad * 8];
                s = __builtin_amdgcn_mfma_f32_16x16x32_bf16(qf[d8], bfr, s, 0, 0, 0);
            }
            const int kpos = k0 + nt * 16 + l16;
            #pragma unroll
            for (int g = 0; g < 4; ++g) {
                const int qpos = q0 + w16 + quad * 4 + g;
                const int d = qpos - kpos;
                const float p = (d >= 0) ? s[g] * exp2f((float)d * LOG2_GAMMA) : 0.0f;
                Ss[w][quad * 4 + g][nt * 16 + l16] = (short)f2bf(p);
            }
        }
        // wave-private Ss: same-wave write->read, compiler inserts lgkmcnt
        // waits; no block barrier needed.

        // O += P.V over 64 keys, all 256 cols for this wave's 16 rows
        {
            const short8 a0 = *(const short8*)&Ss[w][l16][quad * 8];
            const short8 a1 = *(const short8*)&Ss[w][l16][32 + quad * 8];
            #pragma unroll
            for (int f = 0; f < 16; ++f) {
                const short8 b0 = *(const short8*)&Vt[f * 16 + l16][quad * 8];
                o[f] = __builtin_amdgcn_mfma_f32_16x16x32_bf16(a0, b0, o[f], 0, 0, 0);
            }
            #pragma unroll
            for (int f = 0; f < 16; ++f) {
                const short8 b1 = *(const short8*)&Vt[f * 16 + l16][32 + quad * 8];
                o[f] = __builtin_amdgcn_mfma_f32_16x16x32_bf16(a1, b1, o[f], 0, 0, 0);
            }
        }
    }

    #pragma unroll
    for (int f = 0; f < 16; ++f) {
        #pragma unroll
        for (int g = 0; g < 4; ++g) {
            const int qpos = q0 + w16 + quad * 4 + g;
            O[rbase + (size_t)qpos * DH + f * 16 + l16] = o[f][g];
        }
    }
}

// ---------------------------------------------------------------------------
extern "C" void kernel_launch(void* const* d_in, const int* in_sizes, int n_in,
                              void* d_out, int out_size, void* d_ws, size_t ws_size,
                              hipStream_t stream)
{
    const float* X  = (const float*)d_in[0];
    const float* WQ = (const float*)d_in[1];
    const float* WK = (const float*)d_in[2];
    const float* WV = (const float*)d_in[3];
    float* out = (float*)d_out;

    const size_t per = (size_t)BATCH_N * L_SEQ * DH;   // 4,194,304
    unsigned short* Qw  = (unsigned short*)d_ws;
    unsigned short* Kw  = Qw + per;
    unsigned short* Vtw = Kw + per;
    unsigned short* Xbw = Vtw + per;                   // 16,777,216 elems
    unsigned short* Wtw = Xbw + (size_t)16384 * HID;   // 786,432 elems
    // total ~59 MB

    convert_x_kernel<<<16384, 256, 0, stream>>>(X, Xbw);
    transpose_w_kernel<<<dim3(12, 16), 256, 0, stream>>>(WQ, WK, WV, Wtw);

    gemm_qkv_kernel<<<768, 256, 0, stream>>>(Wtw, Xbw, Qw, Kw, Vtw);

    retention_kernel<<<dim3(64, BATCH_N), 256, 0, stream>>>(Qw, Kw, Vtw, out);
}